// Round 11
// baseline (396.894 us; speedup 1.0000x reference)
//
#include <hip/hip_runtime.h>
#include <math.h>

typedef unsigned short ushort_t;
typedef unsigned int uint_t;
typedef __attribute__((ext_vector_type(8))) short short8;
typedef __attribute__((ext_vector_type(4))) float fx4;
typedef __attribute__((ext_vector_type(16))) float f32x16;
typedef __attribute__((ext_vector_type(4))) uint_t uintx4;
typedef __attribute__((ext_vector_type(2))) uint_t uintx2;

__device__ __forceinline__ float bf16_to_f32(ushort_t u) {
    union { uint_t i; float f; } c;
    c.i = ((uint_t)u) << 16;
    return c.f;
}
__device__ __forceinline__ ushort_t f32_to_bf16(float f) {
    union { float f; uint_t i; } c;
    c.f = f;
    const uint_t x = c.i;
    return (ushort_t)((x + 0x7fffu + ((x >> 16) & 1u)) >> 16);
}
// unpack one dword (2 bf16) and FMA into two accumulators
__device__ __forceinline__ void unpack_fma(uint_t w, float p, float& a0,
                                           float& a1) {
    union { uint_t i; float f; } lo, hi;
    lo.i = w << 16;
    hi.i = w & 0xffff0000u;
    a0 += p * lo.f;
    a1 += p * hi.f;
}

// ---- MFMA GEMM, 32x32x16 tiles, B staged in LDS (K-split), fused att ------
// C[n][M](bf16) = A[n][K] * B[K][M]; also writes a_src/a_dst per row:
// head h of layer 1 occupies exactly col-tile t=h (C=32 = tile width), so
// the per-head dot = lane-local multiply + 5-step __shfl_xor butterfly
// over the 32-lane half. Uses pre-bf16-rounding f32 accs (closer to f32
// reference than the separate att pass which re-read rounded h).
// HATT = 4 (layer 1: 4 heads x 32ch) or 1 (layer 2: 1 head x 64ch).
template <int TILES32, bool A_F32, int K, int KS, int HATT>
__global__ __launch_bounds__(256) void gemm32_kernel(
    const void* __restrict__ Avoid, const ushort_t* __restrict__ BT,
    ushort_t* __restrict__ C, const float* __restrict__ att_s,
    const float* __restrict__ att_d, float* __restrict__ as_,
    float* __restrict__ ad_, int n) {
    constexpr int M = TILES32 * 32;
    constexpr int CHS = KS / 8;    // 16B chunks per BT row per stage (16)
    constexpr int NSTEP = KS / 16; // k-steps per stage
    constexpr int NTOT = K / 16;   // total k-steps
    __shared__ ushort_t lds[M * KS];
    const int tid = threadIdx.x;
    const int wave = tid >> 6;
    const int lane = tid & 63;
    const int l31 = lane & 31;
    const int half = lane >> 5;  // 0/1
    const int rowbase = blockIdx.x * 256 + wave * 64;
    const int r0 = min(rowbase + l31, n - 1);
    const int r1 = min(rowbase + 32 + l31, n - 1);
    const size_t off0 = (size_t)r0 * K + half * 8;
    const size_t off1 = (size_t)r1 * K + half * 8;

    f32x16 acc[2][TILES32];
#pragma unroll
    for (int rp = 0; rp < 2; ++rp)
#pragma unroll
        for (int t = 0; t < TILES32; ++t)
#pragma unroll
            for (int i = 0; i < 16; ++i) acc[rp][t][i] = 0.f;

    fx4 c0a, c0b, c1a, c1b, n0a, n0b, n1a, n1b;
    short8 cb0, cb1, nb0, nb1;

    if constexpr (A_F32) {
        const float* A = (const float*)Avoid;
        c0a = *(const fx4*)(A + off0);
        c0b = *(const fx4*)(A + off0 + 4);
        c1a = *(const fx4*)(A + off1);
        c1b = *(const fx4*)(A + off1 + 4);
    } else {
        const ushort_t* A = (const ushort_t*)Avoid;
        cb0 = *(const short8*)(A + off0);
        cb1 = *(const short8*)(A + off1);
    }

#pragma unroll
    for (int ks = 0; ks < K; ks += KS) {
        if (ks) __syncthreads();  // previous stage fully consumed
        // ---- stage BT[:, ks:ks+KS] -> LDS, swizzled ----
#pragma unroll
        for (int i = 0; i < (M * CHS + 255) / 256; ++i) {
            const int idx = tid + i * 256;
            if (idx < M * CHS) {
                const int row = idx / CHS;
                const int c = idx - row * CHS;
                *(short8*)&lds[(size_t)(row * CHS +
                                        (c ^ (row & (CHS - 1)))) * 8] =
                    *(const short8*)(BT + (size_t)row * K + ks + c * 8);
            }
        }
        __syncthreads();

#pragma unroll
        for (int kstep = 0; kstep < NSTEP; ++kstep) {
            const int kg = ks / 16 + kstep;  // global k-step
            if (kg + 1 < NTOT) {
                const int kd = (kg + 1) * 16;
                if constexpr (A_F32) {
                    const float* A = (const float*)Avoid;
                    n0a = *(const fx4*)(A + off0 + kd);
                    n0b = *(const fx4*)(A + off0 + kd + 4);
                    n1a = *(const fx4*)(A + off1 + kd);
                    n1b = *(const fx4*)(A + off1 + kd + 4);
                } else {
                    const ushort_t* A = (const ushort_t*)Avoid;
                    nb0 = *(const short8*)(A + off0 + kd);
                    nb1 = *(const short8*)(A + off1 + kd);
                }
            }
            short8 bf[TILES32];
#pragma unroll
            for (int t = 0; t < TILES32; ++t) {
                const int brow = t * 32 + l31;
                const int c = kstep * 2 + half;
                bf[t] = *(const short8*)&lds[(size_t)(brow * CHS +
                                                      (c ^ (brow &
                                                            (CHS - 1)))) * 8];
            }
            short8 af0, af1;
            if constexpr (A_F32) {
                union { short8 v; ushort_t u[8]; } u0, u1;
#pragma unroll
                for (int j = 0; j < 4; ++j) {
                    u0.u[j] = f32_to_bf16(c0a[j]);
                    u0.u[4 + j] = f32_to_bf16(c0b[j]);
                    u1.u[j] = f32_to_bf16(c1a[j]);
                    u1.u[4 + j] = f32_to_bf16(c1b[j]);
                }
                af0 = u0.v;
                af1 = u1.v;
            } else {
                af0 = cb0;
                af1 = cb1;
            }
#pragma unroll
            for (int t = 0; t < TILES32; ++t) {
                acc[0][t] = __builtin_amdgcn_mfma_f32_32x32x16_bf16(
                    af0, bf[t], acc[0][t], 0, 0, 0);
                acc[1][t] = __builtin_amdgcn_mfma_f32_32x32x16_bf16(
                    af1, bf[t], acc[1][t], 0, 0, 0);
            }
            if (kg + 1 < NTOT) {
                if constexpr (A_F32) {
                    c0a = n0a; c0b = n0b; c1a = n1a; c1b = n1b;
                } else {
                    cb0 = nb0; cb1 = nb1;
                }
            }
        }
    }

    // ---- epilogue: fused att dots + C write ----
    float satt_s[TILES32], satt_d[TILES32];
#pragma unroll
    for (int t = 0; t < TILES32; ++t) {
        satt_s[t] = att_s[t * 32 + l31];
        satt_d[t] = att_d[t * 32 + l31];
    }
#pragma unroll
    for (int rp = 0; rp < 2; ++rp) {
        const int base_r = rowbase + rp * 32 + 4 * half;
#pragma unroll
        for (int reg = 0; reg < 16; ++reg) {
            const int rr = base_r + (reg & 3) + 8 * (reg >> 2);
            float vs[TILES32], vd[TILES32];
#pragma unroll
            for (int t = 0; t < TILES32; ++t) {
                vs[t] = acc[rp][t][reg] * satt_s[t];
                vd[t] = acc[rp][t][reg] * satt_d[t];
            }
            constexpr int NH = (HATT == 1) ? 1 : TILES32;
            if constexpr (HATT == 1) {
#pragma unroll
                for (int t = 1; t < TILES32; ++t) {
                    vs[0] += vs[t];
                    vd[0] += vd[t];
                }
            }
#pragma unroll
            for (int d = 1; d < 32; d <<= 1) {
#pragma unroll
                for (int hh = 0; hh < NH; ++hh) {
                    vs[hh] += __shfl_xor(vs[hh], d);
                    vd[hh] += __shfl_xor(vd[hh], d);
                }
            }
            if (l31 == 0 && rr < n) {
                if constexpr (HATT == 4) {
                    *(fx4*)(as_ + (size_t)rr * 4) =
                        (fx4){vs[0], vs[1], vs[2], vs[3]};
                    *(fx4*)(ad_ + (size_t)rr * 4) =
                        (fx4){vd[0], vd[1], vd[2], vd[3]};
                } else {
                    as_[rr] = vs[0];
                    ad_[rr] = vd[0];
                }
            }
            if (rr < n) {
#pragma unroll
                for (int t = 0; t < TILES32; ++t)
                    C[(size_t)rr * M + t * 32 + l31] =
                        f32_to_bf16(acc[rp][t][reg]);
            }
        }
    }
}

// ------------------- CSR build via binned counting sort -------------------
// (round-7 lesson: direct atomic-cursor scatter to random offsets
// write-allocates 64B lines. Binned writes are per-bucket contiguous.)
// Edge payload packed: src (17b) | (dst & 255) << 17.
// hist kernel also carries the W-transpose work in its tail blocks.
__global__ __launch_bounds__(1024) void hist_kernel(
    const int* __restrict__ dst, int* __restrict__ histG, int e, int chunk,
    int NB, int G, const float* __restrict__ W1, ushort_t* __restrict__ W1T,
    const float* __restrict__ W2, ushort_t* __restrict__ W2T) {
    if (blockIdx.x >= (uint_t)G) {
        // ---- weight transpose + bf16 convert ----
        const int idx = (blockIdx.x - G) * 1024 + threadIdx.x;
        if (idx < 256 * 128) {  // W1: k=256, m=128
            const int mm = idx / 256;
            const int kk = idx - mm * 256;
            W1T[idx] = f32_to_bf16(W1[(size_t)kk * 128 + mm]);
        } else if (idx < 256 * 128 + 128 * 64) {  // W2: k=128, m=64
            const int j = idx - 256 * 128;
            const int mm = j / 128;
            const int kk = j - mm * 128;
            W2T[j] = f32_to_bf16(W2[(size_t)kk * 64 + mm]);
        }
        return;
    }
    __shared__ int hl[512];
    for (int b = threadIdx.x; b < NB; b += 1024) hl[b] = 0;
    __syncthreads();
    const int g = blockIdx.x;
    const int lo = g * chunk;
    const int hi = min(lo + chunk, e);
    for (int i = lo + threadIdx.x; i < hi; i += 1024)
        atomicAdd(&hl[dst[i] >> 8], 1);
    __syncthreads();
    for (int b = threadIdx.x; b < NB; b += 1024) histG[b * G + g] = hl[b];
}

__global__ __launch_bounds__(1024) void scan1_kernel(const int* __restrict__ in,
                                                     int* __restrict__ out,
                                                     int* __restrict__ sums,
                                                     int n) {
    __shared__ int s[1024];
    const int t = threadIdx.x;
    const int i = blockIdx.x * 1024 + t;
    const int v = (i < n) ? in[i] : 0;
    s[t] = v;
    __syncthreads();
    for (int d = 1; d < 1024; d <<= 1) {
        const int x = (t >= d) ? s[t - d] : 0;
        __syncthreads();
        s[t] += x;
        __syncthreads();
    }
    if (i < n) out[i] = s[t] - v;
    if (t == 1023) sums[blockIdx.x] = s[1023];
}

// scan3 with internal exclusive prefix of the (<=64) block sums: first
// wave butterfly-sums sums[j], j < blockIdx.x (replaces separate scan2).
__global__ __launch_bounds__(1024) void scan3_kernel(
    int* __restrict__ out, const int* __restrict__ sums, int n, int nb) {
    __shared__ int offsh;
    if (threadIdx.x < 64) {
        const int t = threadIdx.x;
        int v = (t < nb && t < (int)blockIdx.x) ? sums[t] : 0;
#pragma unroll
        for (int d = 1; d < 64; d <<= 1) v += __shfl_xor(v, d);
        if (t == 0) offsh = v;
    }
    __syncthreads();
    const int i = blockIdx.x * 1024 + threadIdx.x;
    if (i < n) out[i] += offsh;
}

__global__ __launch_bounds__(1024) void bin_kernel(const int* __restrict__ src,
                                                   const int* __restrict__ dst,
                                                   const int* __restrict__ base,
                                                   uint_t* __restrict__ binned,
                                                   int e, int chunk, int NB,
                                                   int G) {
    __shared__ int cur[512];
    const int g = blockIdx.x;
    for (int b = threadIdx.x; b < NB; b += 1024) cur[b] = base[b * G + g];
    __syncthreads();
    const int lo = g * chunk;
    const int hi = min(lo + chunk, e);
    for (int i = lo + threadIdx.x; i < hi; i += 1024) {
        const int d = dst[i];
        const int p = atomicAdd(&cur[d >> 8], 1);
        binned[p] = (uint_t)src[i] | ((uint_t)(d & 255) << 17);
    }
}

#define BUILD_CAP 6144
__global__ __launch_bounds__(256) void build_kernel(
    const uint_t* __restrict__ binned, const int* __restrict__ base,
    int* __restrict__ csr, int* __restrict__ deg, int* __restrict__ offs,
    int e, int n, int NB, int G) {
    __shared__ uint_t ep[BUILD_CAP];
    __shared__ int degL[256];
    __shared__ int offL[256];
    __shared__ int curL[256];
    const int b = blockIdx.x;
    const int tid = threadIdx.x;
    const int start = base[b * G];
    const int end = (b == NB - 1) ? e : base[(b + 1) * G];
    const int cnt = end - start;
    const bool stage = (cnt <= BUILD_CAP);
    degL[tid] = 0;
    if (stage)
        for (int i = tid; i < cnt; i += 256) ep[i] = binned[start + i];
    __syncthreads();
    if (stage) {
        for (int i = tid; i < cnt; i += 256)
            atomicAdd(&degL[ep[i] >> 17], 1);
    } else {
        for (int i = tid; i < cnt; i += 256)
            atomicAdd(&degL[binned[start + i] >> 17], 1);
    }
    __syncthreads();
    const int v = degL[tid];
    offL[tid] = v;
    __syncthreads();
    for (int d = 1; d < 256; d <<= 1) {
        const int x = (tid >= d) ? offL[tid - d] : 0;
        __syncthreads();
        offL[tid] += x;
        __syncthreads();
    }
    const int excl = offL[tid] - v;
    curL[tid] = excl;
    const int node = (b << 8) + tid;
    if (node < n) {
        deg[node] = v;
        offs[node] = start + excl;
    }
    __syncthreads();
    if (stage) {
        for (int i = tid; i < cnt; i += 256) {
            const uint_t pr = ep[i];
            const int p = atomicAdd(&curL[pr >> 17], 1);
            csr[start + p] = (int)(pr & 0x1FFFFu);
        }
    } else {
        for (int i = tid; i < cnt; i += 256) {
            const uint_t pr = binned[start + i];
            const int p = atomicAdd(&curL[pr >> 17], 1);
            csr[start + p] = (int)(pr & 0x1FFFFu);
        }
    }
}

// --------- single-pass gather-aggregate + fused softmax denominator -------
// 4 nodes per wave, 16 lanes per node. At the random-gather fabric floor
// (rounds 1/3/4/6: four structural variants all 76-77us; 248MB L2-miss
// traffic served at ~3.7TB/s). Do not re-optimize issue shape.
template <int H, int C, bool DO_ELU, bool OUT_BF16>
__global__ __launch_bounds__(64) void agg_kernel(
    const ushort_t* __restrict__ h, const float* __restrict__ a_src,
    const float* __restrict__ a_dst, const int* __restrict__ csr,
    const int* __restrict__ offs, const int* __restrict__ deg,
    const float* __restrict__ bias, void* __restrict__ outv, int n) {
    constexpr int HC = H * C;
    constexpr int R = HC / 16;   // 8 (layer1) or 4 (layer2) channels/lane
    constexpr int RW = R / 2;    // dwords per h access (4 or 2)
    constexpr int U = 4;         // edge batch
    const int lane = threadIdx.x;
    const int s = lane & 15;
    const int g = lane >> 4;
    const int dst = blockIdx.x * 4 + g;
    const int dstc = min(dst, n - 1);
    const int start = offs[dstc];
    const int dg = deg[dstc];
    const int ch0 = s * R;
    const int myh = (H > 1) ? (ch0 / C) : 0;
    const float advm = a_dst[dstc * H + myh];

    // wave-uniform loop bound: max degree over the 4 node groups
    int dmax = dg;
    dmax = max(dmax, __shfl_xor(dmax, 16));
    dmax = max(dmax, __shfl_xor(dmax, 32));
    dmax = __builtin_amdgcn_readfirstlane(dmax);

    float acc[R];
#pragma unroll
    for (int r = 0; r < R; ++r) acc[r] = 0.f;
    float L = 0.f;

    // ---- self-loop term ----
    {
        float e = a_src[dstc * H + myh] + advm;
        e = fmaxf(e, 0.2f * e);
        const float p = __expf(e);
        L += p;
        const ushort_t* hp = h + (size_t)((uint_t)dstc * HC) + ch0;
        if constexpr (RW == 4) {
            const uintx4 v = *(const uintx4*)hp;
#pragma unroll
            for (int w = 0; w < 4; ++w)
                unpack_fma(v[w], p, acc[2 * w], acc[2 * w + 1]);
        } else {
            const uintx2 v = *(const uintx2*)hp;
#pragma unroll
            for (int w = 0; w < 2; ++w)
                unpack_fma(v[w], p, acc[2 * w], acc[2 * w + 1]);
        }
    }

    const int dm1c = (dg > 0) ? dg - 1 : 0;

    for (int j0 = 0; j0 < dmax; j0 += U) {
        int sv[U];
#pragma unroll
        for (int u = 0; u < U; ++u)
            sv[u] = csr[start + min(j0 + u, dm1c)];
        float es[U];
#pragma unroll
        for (int u = 0; u < U; ++u) es[u] = a_src[sv[u] * H + myh];
        uint_t hv[U][RW];
#pragma unroll
        for (int u = 0; u < U; ++u) {
            const ushort_t* hp = h + (size_t)((uint_t)sv[u] * HC) + ch0;
            if constexpr (RW == 4) {
                const uintx4 v = *(const uintx4*)hp;
#pragma unroll
                for (int w = 0; w < 4; ++w) hv[u][w] = v[w];
            } else {
                const uintx2 v = *(const uintx2*)hp;
#pragma unroll
                for (int w = 0; w < 2; ++w) hv[u][w] = v[w];
            }
        }
        float p[U];
#pragma unroll
        for (int u = 0; u < U; ++u) {
            float e = es[u] + advm;
            e = fmaxf(e, 0.2f * e);
            const float pe = __expf(e);
            p[u] = (j0 + u < dg) ? pe : 0.f;
        }
#pragma unroll
        for (int u = 0; u < U; ++u) {
            L += p[u];
#pragma unroll
            for (int w = 0; w < RW; ++w)
                unpack_fma(hv[u][w], p[u], acc[2 * w], acc[2 * w + 1]);
        }
    }

    if (dst >= n) return;
    const float linv = 1.f / (L + 1e-16f);
    float r[R];
#pragma unroll
    for (int d = 0; d < R; ++d) {
        r[d] = acc[d] * linv + bias[ch0 + d];
        if (DO_ELU) r[d] = (r[d] > 0.f) ? r[d] : (__expf(r[d]) - 1.f);
    }
    if constexpr (OUT_BF16) {
        uintx4 o;
#pragma unroll
        for (int w = 0; w < 4; ++w)
            o[w] = (uint_t)f32_to_bf16(r[2 * w]) |
                   ((uint_t)f32_to_bf16(r[2 * w + 1]) << 16);
        *(uintx4*)((ushort_t*)outv + (size_t)dst * HC + ch0) = o;
    } else {
        fx4 o;
#pragma unroll
        for (int d = 0; d < 4; ++d) o[d] = r[d];
        *(fx4*)((float*)outv + (size_t)dst * HC + ch0) = o;
    }
}

// --------------------------------------------------------------------------
extern "C" void kernel_launch(void* const* d_in, const int* in_sizes, int n_in,
                              void* d_out, int out_size, void* d_ws,
                              size_t ws_size, hipStream_t stream) {
    const float* x = (const float*)d_in[0];
    const int* ei = (const int*)d_in[1];
    const float* W1 = (const float*)d_in[2];
    const float* att_s1 = (const float*)d_in[3];
    const float* att_d1 = (const float*)d_in[4];
    const float* b1 = (const float*)d_in[5];
    const float* W2 = (const float*)d_in[6];
    const float* att_s2 = (const float*)d_in[7];
    const float* att_d2 = (const float*)d_in[8];
    const float* b2 = (const float*)d_in[9];

    const int N = in_sizes[0] / 256;  // 100000
    const int E = in_sizes[1] / 2;    // 1600000
    const int* srcp = ei;
    const int* dstp = ei + E;

    const int NB = (N + 255) >> 8;  // 391 buckets of 256 nodes
    const int G = 128;
    const int NBG = NB * G;
    const int chunk = (E + G - 1) / G;
    const int nbs = (NBG + 1023) / 1024;  // 49 (<= 64 required by scan3)

    // workspace layout
    float* as1 = (float*)d_ws;           // N*4
    float* ad1 = as1 + (size_t)N * 4;    // N*4
    float* as2 = ad1 + (size_t)N * 4;    // N
    float* ad2 = as2 + N;                // N
    int* histG = (int*)(ad2 + N);        // NBG
    int* base = histG + NBG;             // NBG
    int* sums = base + NBG;              // 128
    int* deg = sums + 128;               // N
    int* offs = deg + N;                 // N
    int* csr = offs + N;                 // E
    uint_t* binned = (uint_t*)(csr + E); // E packed (dead after build)
    ushort_t* h1 = (ushort_t*)binned;    // N*128 bf16 (overlays binned)
    ushort_t* h2 = h1 + (size_t)N * 128; // N*64 bf16
    ushort_t* h1p = h2 + (size_t)N * 64; // N*128 bf16 (agg1 out, gemm2 A)
    ushort_t* W1T = h1p + (size_t)N * 128;  // 128*256
    ushort_t* W2T = W1T + 128 * 256;        // 64*128

    // ---- CSR build (binned counting sort) + fused W transpose ----
    const int cvblk = (256 * 128 + 128 * 64 + 1023) / 1024;  // 40
    hist_kernel<<<G + cvblk, 1024, 0, stream>>>(dstp, histG, E, chunk, NB, G,
                                                W1, W1T, W2, W2T);
    scan1_kernel<<<nbs, 1024, 0, stream>>>(histG, base, sums, NBG);
    scan3_kernel<<<nbs, 1024, 0, stream>>>(base, sums, NBG, nbs);
    bin_kernel<<<G, 1024, 0, stream>>>(srcp, dstp, base, binned, E, chunk, NB,
                                       G);
    build_kernel<<<NB, 256, 0, stream>>>(binned, base, csr, deg, offs, E, N,
                                         NB, G);

    const int gblk = (N + 255) / 256;  // 391 (256 rows per block)
    const int ablk = (N + 3) / 4;      // 25000 (4 nodes per wave)

    // ---- layer 1 (gemm + fused att) ----
    gemm32_kernel<4, true, 256, 128, 4><<<gblk, 256, 0, stream>>>(
        x, W1T, h1, att_s1, att_d1, as1, ad1, N);
    agg_kernel<4, 32, true, true><<<ablk, 64, 0, stream>>>(h1, as1, ad1, csr,
                                                           offs, deg, b1, h1p,
                                                           N);

    // ---- layer 2 (gemm + fused att) ----
    gemm32_kernel<2, false, 128, 128, 1><<<gblk, 256, 0, stream>>>(
        h1p, W2T, h2, att_s2, att_d2, as2, ad2, N);
    agg_kernel<1, 64, false, false><<<ablk, 64, 0, stream>>>(
        h2, as2, ad2, csr, offs, deg, b2, d_out, N);
}

// Round 12
// 382.817 us; speedup vs baseline: 1.0368x; 1.0368x over previous
//
#include <hip/hip_runtime.h>
#include <math.h>

typedef unsigned short ushort_t;
typedef unsigned int uint_t;
typedef __attribute__((ext_vector_type(8))) short short8;
typedef __attribute__((ext_vector_type(4))) float fx4;
typedef __attribute__((ext_vector_type(16))) float f32x16;
typedef __attribute__((ext_vector_type(4))) uint_t uintx4;
typedef __attribute__((ext_vector_type(2))) uint_t uintx2;

__device__ __forceinline__ float bf16_to_f32(ushort_t u) {
    union { uint_t i; float f; } c;
    c.i = ((uint_t)u) << 16;
    return c.f;
}
__device__ __forceinline__ ushort_t f32_to_bf16(float f) {
    union { float f; uint_t i; } c;
    c.f = f;
    const uint_t x = c.i;
    return (ushort_t)((x + 0x7fffu + ((x >> 16) & 1u)) >> 16);
}
// unpack one dword (2 bf16) and FMA into two accumulators
__device__ __forceinline__ void unpack_fma(uint_t w, float p, float& a0,
                                           float& a1) {
    union { uint_t i; float f; } lo, hi;
    lo.i = w << 16;
    hi.i = w & 0xffff0000u;
    a0 += p * lo.f;
    a1 += p * hi.f;
}

// ---- MFMA GEMM, 32x32x16 tiles, B staged in LDS (K-split) -----------------
// Occupancy-restructured (round-11 counters: 391 blocks -> 1.5/CU, occ
// 8.3%, all pipes idle = latency-bound, NOT LDS-bound as round-9 assumed):
// 1 row-tile (32 rows) per wave, 128 rows/block -> 782 blocks (3/CU) and
// ~110 VGPR -> 4 waves/SIMD. LDS reads/row double (acceptable; LDS idle),
// BT re-stage is L2/L3-resident. No att fusion (round-11: 1280 shuffles
// per thread cost ~30us; separate att pass is ~10us).
template <int TILES32, bool A_F32, int K, int KS>
__global__ __launch_bounds__(256) void gemm32_kernel(
    const void* __restrict__ Avoid, const ushort_t* __restrict__ BT,
    ushort_t* __restrict__ C, int n) {
    constexpr int M = TILES32 * 32;
    constexpr int CHS = KS / 8;    // 16B chunks per BT row per stage (16)
    constexpr int NSTEP = KS / 16; // k-steps per stage
    constexpr int NTOT = K / 16;   // total k-steps
    __shared__ ushort_t lds[M * KS];
    const int tid = threadIdx.x;
    const int wave = tid >> 6;
    const int lane = tid & 63;
    const int l31 = lane & 31;
    const int half = lane >> 5;  // 0/1
    const int rowbase = blockIdx.x * 128 + wave * 32;
    const int r0 = min(rowbase + l31, n - 1);
    const size_t off0 = (size_t)r0 * K + half * 8;

    f32x16 acc[TILES32];
#pragma unroll
    for (int t = 0; t < TILES32; ++t)
#pragma unroll
        for (int i = 0; i < 16; ++i) acc[t][i] = 0.f;

    fx4 c0a, c0b, n0a, n0b;
    short8 cb0, nb0;

    if constexpr (A_F32) {
        const float* A = (const float*)Avoid;
        c0a = *(const fx4*)(A + off0);
        c0b = *(const fx4*)(A + off0 + 4);
    } else {
        const ushort_t* A = (const ushort_t*)Avoid;
        cb0 = *(const short8*)(A + off0);
    }

#pragma unroll
    for (int ks = 0; ks < K; ks += KS) {
        if (ks) __syncthreads();  // previous stage fully consumed
        // ---- stage BT[:, ks:ks+KS] -> LDS, swizzled ----
#pragma unroll
        for (int i = 0; i < (M * CHS + 255) / 256; ++i) {
            const int idx = tid + i * 256;
            if (idx < M * CHS) {
                const int row = idx / CHS;
                const int c = idx - row * CHS;
                *(short8*)&lds[(size_t)(row * CHS +
                                        (c ^ (row & (CHS - 1)))) * 8] =
                    *(const short8*)(BT + (size_t)row * K + ks + c * 8);
            }
        }
        __syncthreads();

#pragma unroll
        for (int kstep = 0; kstep < NSTEP; ++kstep) {
            const int kg = ks / 16 + kstep;  // global k-step
            if (kg + 1 < NTOT) {
                const int kd = (kg + 1) * 16;
                if constexpr (A_F32) {
                    const float* A = (const float*)Avoid;
                    n0a = *(const fx4*)(A + off0 + kd);
                    n0b = *(const fx4*)(A + off0 + kd + 4);
                } else {
                    const ushort_t* A = (const ushort_t*)Avoid;
                    nb0 = *(const short8*)(A + off0 + kd);
                }
            }
            short8 bf[TILES32];
#pragma unroll
            for (int t = 0; t < TILES32; ++t) {
                const int brow = t * 32 + l31;
                const int c = kstep * 2 + half;
                bf[t] = *(const short8*)&lds[(size_t)(brow * CHS +
                                                      (c ^ (brow &
                                                            (CHS - 1)))) * 8];
            }
            short8 af0;
            if constexpr (A_F32) {
                union { short8 v; ushort_t u[8]; } u0;
#pragma unroll
                for (int j = 0; j < 4; ++j) {
                    u0.u[j] = f32_to_bf16(c0a[j]);
                    u0.u[4 + j] = f32_to_bf16(c0b[j]);
                }
                af0 = u0.v;
            } else {
                af0 = cb0;
            }
#pragma unroll
            for (int t = 0; t < TILES32; ++t) {
                acc[t] = __builtin_amdgcn_mfma_f32_32x32x16_bf16(
                    af0, bf[t], acc[t], 0, 0, 0);
            }
            if (kg + 1 < NTOT) {
                if constexpr (A_F32) {
                    c0a = n0a; c0b = n0b;
                } else {
                    cb0 = nb0;
                }
            }
        }
    }

    const int base_r = rowbase + 4 * half;
#pragma unroll
    for (int t = 0; t < TILES32; ++t) {
        const int col = t * 32 + l31;
#pragma unroll
        for (int reg = 0; reg < 16; ++reg) {
            const int rr = base_r + (reg & 3) + 8 * (reg >> 2);
            if (rr < n) C[(size_t)rr * M + col] = f32_to_bf16(acc[t][reg]);
        }
    }
}

// ------------- per-node attention coefficients a_src, a_dst ---------------
template <int H, int C>
__global__ void att_kernel(const ushort_t* __restrict__ h,
                           const float* __restrict__ att_s,
                           const float* __restrict__ att_d,
                           float* __restrict__ as_, float* __restrict__ ad_,
                           int n) {
    const int idx = blockIdx.x * blockDim.x + threadIdx.x;
    if (idx >= n * H) return;
    const int node = idx / H;
    const int hh = idx % H;
    const ushort_t* hp = h + (size_t)node * H * C + hh * C;
    float s0 = 0.f, s1 = 0.f;
#pragma unroll
    for (int c = 0; c < C; ++c) {
        const float v = bf16_to_f32(hp[c]);
        s0 += v * att_s[hh * C + c];
        s1 += v * att_d[hh * C + c];
    }
    as_[idx] = s0;
    ad_[idx] = s1;
}

// ------------------- CSR build via binned counting sort -------------------
// (round-7 lesson: direct atomic-cursor scatter to random offsets
// write-allocates 64B lines. Binned writes are per-bucket contiguous.)
// Edge payload packed: src (17b) | (dst & 255) << 17.
// hist kernel also carries the W-transpose work in its tail blocks.
__global__ __launch_bounds__(1024) void hist_kernel(
    const int* __restrict__ dst, int* __restrict__ histG, int e, int chunk,
    int NB, int G, const float* __restrict__ W1, ushort_t* __restrict__ W1T,
    const float* __restrict__ W2, ushort_t* __restrict__ W2T) {
    if (blockIdx.x >= (uint_t)G) {
        // ---- weight transpose + bf16 convert ----
        const int idx = (blockIdx.x - G) * 1024 + threadIdx.x;
        if (idx < 256 * 128) {  // W1: k=256, m=128
            const int mm = idx / 256;
            const int kk = idx - mm * 256;
            W1T[idx] = f32_to_bf16(W1[(size_t)kk * 128 + mm]);
        } else if (idx < 256 * 128 + 128 * 64) {  // W2: k=128, m=64
            const int j = idx - 256 * 128;
            const int mm = j / 128;
            const int kk = j - mm * 128;
            W2T[j] = f32_to_bf16(W2[(size_t)kk * 64 + mm]);
        }
        return;
    }
    __shared__ int hl[512];
    for (int b = threadIdx.x; b < NB; b += 1024) hl[b] = 0;
    __syncthreads();
    const int g = blockIdx.x;
    const int lo = g * chunk;
    const int hi = min(lo + chunk, e);
    for (int i = lo + threadIdx.x; i < hi; i += 1024)
        atomicAdd(&hl[dst[i] >> 8], 1);
    __syncthreads();
    for (int b = threadIdx.x; b < NB; b += 1024) histG[b * G + g] = hl[b];
}

__global__ __launch_bounds__(1024) void scan1_kernel(const int* __restrict__ in,
                                                     int* __restrict__ out,
                                                     int* __restrict__ sums,
                                                     int n) {
    __shared__ int s[1024];
    const int t = threadIdx.x;
    const int i = blockIdx.x * 1024 + t;
    const int v = (i < n) ? in[i] : 0;
    s[t] = v;
    __syncthreads();
    for (int d = 1; d < 1024; d <<= 1) {
        const int x = (t >= d) ? s[t - d] : 0;
        __syncthreads();
        s[t] += x;
        __syncthreads();
    }
    if (i < n) out[i] = s[t] - v;
    if (t == 1023) sums[blockIdx.x] = s[1023];
}

// scan3 with internal exclusive prefix of the (<=64) block sums: first
// wave butterfly-sums sums[j], j < blockIdx.x (replaces separate scan2).
__global__ __launch_bounds__(1024) void scan3_kernel(
    int* __restrict__ out, const int* __restrict__ sums, int n, int nb) {
    __shared__ int offsh;
    if (threadIdx.x < 64) {
        const int t = threadIdx.x;
        int v = (t < nb && t < (int)blockIdx.x) ? sums[t] : 0;
#pragma unroll
        for (int d = 1; d < 64; d <<= 1) v += __shfl_xor(v, d);
        if (t == 0) offsh = v;
    }
    __syncthreads();
    const int i = blockIdx.x * 1024 + threadIdx.x;
    if (i < n) out[i] += offsh;
}

__global__ __launch_bounds__(1024) void bin_kernel(const int* __restrict__ src,
                                                   const int* __restrict__ dst,
                                                   const int* __restrict__ base,
                                                   uint_t* __restrict__ binned,
                                                   int e, int chunk, int NB,
                                                   int G) {
    __shared__ int cur[512];
    const int g = blockIdx.x;
    for (int b = threadIdx.x; b < NB; b += 1024) cur[b] = base[b * G + g];
    __syncthreads();
    const int lo = g * chunk;
    const int hi = min(lo + chunk, e);
    for (int i = lo + threadIdx.x; i < hi; i += 1024) {
        const int d = dst[i];
        const int p = atomicAdd(&cur[d >> 8], 1);
        binned[p] = (uint_t)src[i] | ((uint_t)(d & 255) << 17);
    }
}

#define BUILD_CAP 6144
__global__ __launch_bounds__(256) void build_kernel(
    const uint_t* __restrict__ binned, const int* __restrict__ base,
    int* __restrict__ csr, int* __restrict__ deg, int* __restrict__ offs,
    int e, int n, int NB, int G) {
    __shared__ uint_t ep[BUILD_CAP];
    __shared__ int degL[256];
    __shared__ int offL[256];
    __shared__ int curL[256];
    const int b = blockIdx.x;
    const int tid = threadIdx.x;
    const int start = base[b * G];
    const int end = (b == NB - 1) ? e : base[(b + 1) * G];
    const int cnt = end - start;
    const bool stage = (cnt <= BUILD_CAP);
    degL[tid] = 0;
    if (stage)
        for (int i = tid; i < cnt; i += 256) ep[i] = binned[start + i];
    __syncthreads();
    if (stage) {
        for (int i = tid; i < cnt; i += 256)
            atomicAdd(&degL[ep[i] >> 17], 1);
    } else {
        for (int i = tid; i < cnt; i += 256)
            atomicAdd(&degL[binned[start + i] >> 17], 1);
    }
    __syncthreads();
    const int v = degL[tid];
    offL[tid] = v;
    __syncthreads();
    for (int d = 1; d < 256; d <<= 1) {
        const int x = (tid >= d) ? offL[tid - d] : 0;
        __syncthreads();
        offL[tid] += x;
        __syncthreads();
    }
    const int excl = offL[tid] - v;
    curL[tid] = excl;
    const int node = (b << 8) + tid;
    if (node < n) {
        deg[node] = v;
        offs[node] = start + excl;
    }
    __syncthreads();
    if (stage) {
        for (int i = tid; i < cnt; i += 256) {
            const uint_t pr = ep[i];
            const int p = atomicAdd(&curL[pr >> 17], 1);
            csr[start + p] = (int)(pr & 0x1FFFFu);
        }
    } else {
        for (int i = tid; i < cnt; i += 256) {
            const uint_t pr = binned[start + i];
            const int p = atomicAdd(&curL[pr >> 17], 1);
            csr[start + p] = (int)(pr & 0x1FFFFu);
        }
    }
}

// --------- single-pass gather-aggregate + fused softmax denominator -------
// 4 nodes per wave, 16 lanes per node. At the random-gather fabric floor
// (rounds 1/3/4/6: four structural variants all 76-77us; 248MB L2-miss
// traffic served at ~3.7TB/s). Do not re-optimize issue shape.
template <int H, int C, bool DO_ELU, bool OUT_BF16>
__global__ __launch_bounds__(64) void agg_kernel(
    const ushort_t* __restrict__ h, const float* __restrict__ a_src,
    const float* __restrict__ a_dst, const int* __restrict__ csr,
    const int* __restrict__ offs, const int* __restrict__ deg,
    const float* __restrict__ bias, void* __restrict__ outv, int n) {
    constexpr int HC = H * C;
    constexpr int R = HC / 16;   // 8 (layer1) or 4 (layer2) channels/lane
    constexpr int RW = R / 2;    // dwords per h access (4 or 2)
    constexpr int U = 4;         // edge batch
    const int lane = threadIdx.x;
    const int s = lane & 15;
    const int g = lane >> 4;
    const int dst = blockIdx.x * 4 + g;
    const int dstc = min(dst, n - 1);
    const int start = offs[dstc];
    const int dg = deg[dstc];
    const int ch0 = s * R;
    const int myh = (H > 1) ? (ch0 / C) : 0;
    const float advm = a_dst[dstc * H + myh];

    // wave-uniform loop bound: max degree over the 4 node groups
    int dmax = dg;
    dmax = max(dmax, __shfl_xor(dmax, 16));
    dmax = max(dmax, __shfl_xor(dmax, 32));
    dmax = __builtin_amdgcn_readfirstlane(dmax);

    float acc[R];
#pragma unroll
    for (int r = 0; r < R; ++r) acc[r] = 0.f;
    float L = 0.f;

    // ---- self-loop term ----
    {
        float e = a_src[dstc * H + myh] + advm;
        e = fmaxf(e, 0.2f * e);
        const float p = __expf(e);
        L += p;
        const ushort_t* hp = h + (size_t)((uint_t)dstc * HC) + ch0;
        if constexpr (RW == 4) {
            const uintx4 v = *(const uintx4*)hp;
#pragma unroll
            for (int w = 0; w < 4; ++w)
                unpack_fma(v[w], p, acc[2 * w], acc[2 * w + 1]);
        } else {
            const uintx2 v = *(const uintx2*)hp;
#pragma unroll
            for (int w = 0; w < 2; ++w)
                unpack_fma(v[w], p, acc[2 * w], acc[2 * w + 1]);
        }
    }

    const int dm1c = (dg > 0) ? dg - 1 : 0;

    for (int j0 = 0; j0 < dmax; j0 += U) {
        int sv[U];
#pragma unroll
        for (int u = 0; u < U; ++u)
            sv[u] = csr[start + min(j0 + u, dm1c)];
        float es[U];
#pragma unroll
        for (int u = 0; u < U; ++u) es[u] = a_src[sv[u] * H + myh];
        uint_t hv[U][RW];
#pragma unroll
        for (int u = 0; u < U; ++u) {
            const ushort_t* hp = h + (size_t)((uint_t)sv[u] * HC) + ch0;
            if constexpr (RW == 4) {
                const uintx4 v = *(const uintx4*)hp;
#pragma unroll
                for (int w = 0; w < 4; ++w) hv[u][w] = v[w];
            } else {
                const uintx2 v = *(const uintx2*)hp;
#pragma unroll
                for (int w = 0; w < 2; ++w) hv[u][w] = v[w];
            }
        }
        float p[U];
#pragma unroll
        for (int u = 0; u < U; ++u) {
            float e = es[u] + advm;
            e = fmaxf(e, 0.2f * e);
            const float pe = __expf(e);
            p[u] = (j0 + u < dg) ? pe : 0.f;
        }
#pragma unroll
        for (int u = 0; u < U; ++u) {
            L += p[u];
#pragma unroll
            for (int w = 0; w < RW; ++w)
                unpack_fma(hv[u][w], p[u], acc[2 * w], acc[2 * w + 1]);
        }
    }

    if (dst >= n) return;
    const float linv = 1.f / (L + 1e-16f);
    float r[R];
#pragma unroll
    for (int d = 0; d < R; ++d) {
        r[d] = acc[d] * linv + bias[ch0 + d];
        if (DO_ELU) r[d] = (r[d] > 0.f) ? r[d] : (__expf(r[d]) - 1.f);
    }
    if constexpr (OUT_BF16) {
        uintx4 o;
#pragma unroll
        for (int w = 0; w < 4; ++w)
            o[w] = (uint_t)f32_to_bf16(r[2 * w]) |
                   ((uint_t)f32_to_bf16(r[2 * w + 1]) << 16);
        *(uintx4*)((ushort_t*)outv + (size_t)dst * HC + ch0) = o;
    } else {
        fx4 o;
#pragma unroll
        for (int d = 0; d < 4; ++d) o[d] = r[d];
        *(fx4*)((float*)outv + (size_t)dst * HC + ch0) = o;
    }
}

// --------------------------------------------------------------------------
extern "C" void kernel_launch(void* const* d_in, const int* in_sizes, int n_in,
                              void* d_out, int out_size, void* d_ws,
                              size_t ws_size, hipStream_t stream) {
    const float* x = (const float*)d_in[0];
    const int* ei = (const int*)d_in[1];
    const float* W1 = (const float*)d_in[2];
    const float* att_s1 = (const float*)d_in[3];
    const float* att_d1 = (const float*)d_in[4];
    const float* b1 = (const float*)d_in[5];
    const float* W2 = (const float*)d_in[6];
    const float* att_s2 = (const float*)d_in[7];
    const float* att_d2 = (const float*)d_in[8];
    const float* b2 = (const float*)d_in[9];

    const int N = in_sizes[0] / 256;  // 100000
    const int E = in_sizes[1] / 2;    // 1600000
    const int* srcp = ei;
    const int* dstp = ei + E;

    const int NB = (N + 255) >> 8;  // 391 buckets of 256 nodes
    const int G = 128;
    const int NBG = NB * G;
    const int chunk = (E + G - 1) / G;
    const int nbs = (NBG + 1023) / 1024;  // 49 (<= 64 required by scan3)

    // workspace layout
    float* as1 = (float*)d_ws;           // N*4
    float* ad1 = as1 + (size_t)N * 4;    // N*4
    float* as2 = ad1 + (size_t)N * 4;    // N
    float* ad2 = as2 + N;                // N
    int* histG = (int*)(ad2 + N);        // NBG
    int* base = histG + NBG;             // NBG
    int* sums = base + NBG;              // 128
    int* deg = sums + 128;               // N
    int* offs = deg + N;                 // N
    int* csr = offs + N;                 // E
    uint_t* binned = (uint_t*)(csr + E); // E packed (dead after build)
    ushort_t* h1 = (ushort_t*)binned;    // N*128 bf16 (overlays binned)
    ushort_t* h2 = h1 + (size_t)N * 128; // N*64 bf16
    ushort_t* h1p = h2 + (size_t)N * 64; // N*128 bf16 (agg1 out, gemm2 A)
    ushort_t* W1T = h1p + (size_t)N * 128;  // 128*256
    ushort_t* W2T = W1T + 128 * 256;        // 64*128

    // ---- CSR build (binned counting sort) + fused W transpose ----
    const int cvblk = (256 * 128 + 128 * 64 + 1023) / 1024;  // 40
    hist_kernel<<<G + cvblk, 1024, 0, stream>>>(dstp, histG, E, chunk, NB, G,
                                                W1, W1T, W2, W2T);
    scan1_kernel<<<nbs, 1024, 0, stream>>>(histG, base, sums, NBG);
    scan3_kernel<<<nbs, 1024, 0, stream>>>(base, sums, NBG, nbs);
    bin_kernel<<<G, 1024, 0, stream>>>(srcp, dstp, base, binned, E, chunk, NB,
                                       G);
    build_kernel<<<NB, 256, 0, stream>>>(binned, base, csr, deg, offs, E, N,
                                         NB, G);

    const int gblk = (N + 127) / 128;  // 782 (128 rows per block)
    const int ablk = (N + 3) / 4;      // 25000 (4 nodes per wave)

    // ---- layer 1 ----
    gemm32_kernel<4, true, 256, 128><<<gblk, 256, 0, stream>>>(x, W1T, h1, N);
    att_kernel<4, 32><<<(N * 4 + 255) / 256, 256, 0, stream>>>(h1, att_s1,
                                                               att_d1, as1,
                                                               ad1, N);
    agg_kernel<4, 32, true, true><<<ablk, 64, 0, stream>>>(h1, as1, ad1, csr,
                                                           offs, deg, b1, h1p,
                                                           N);

    // ---- layer 2 ----
    gemm32_kernel<2, false, 128, 128><<<gblk, 256, 0, stream>>>(h1p, W2T, h2,
                                                                N);
    att_kernel<1, 64><<<(N + 255) / 256, 256, 0, stream>>>(h2, att_s2, att_d2,
                                                           as2, ad2, N);
    agg_kernel<1, 64, false, false><<<ablk, 64, 0, stream>>>(h2, as2, ad2,
                                                             csr, offs, deg,
                                                             b2, d_out, N);
}